// Round 4
// baseline (175.293 us; speedup 1.0000x reference)
//
#include <hip/hip_runtime.h>

// Problem constants (match reference)
constexpr int B = 32, N = 256, C = 3, H = 512, W = 512, K = 32;

typedef float f32x4 __attribute__((ext_vector_type(4)));

// Block = 256 threads, covering 4 (bn,c) cells (one cell = 32 rows x 8
// float4-chunks = 256 chunks). The gaussian chunk depends only on
// threadIdx.x -> loaded once per thread (saves 75 MB of redundant L1
// traffic vs 1 cell/block). 4 independent load->store chains per thread
// give memory-level ILP.
__global__ __launch_bounds__(256) void rgte_kernel(
    const float* __restrict__ img,
    const int*   __restrict__ mu,
    const float* __restrict__ gauss,
    float*       __restrict__ out)
{
    const int local = threadIdx.x;
    const int kx4   = local & 7;   // 8 float4 per K-row
    const int ky    = local >> 3;  // 32 rows

    // Gaussian chunk: 16B-aligned, L1-resident (4 KB total), uniform over cells.
    const f32x4 g = *reinterpret_cast<const f32x4*>(gauss + ky * K + kx4 * 4);

#pragma unroll
    for (int j = 0; j < 4; ++j) {
        const int rem = blockIdx.x * 4 + j;  // bn*C + c  (grid = B*N*C/4)
        const int c   = rem % 3;
        const int bn  = rem / 3;             // b*N + n
        const int b   = bn >> 8;             // N = 256

        // Block-uniform -> SGPR math + s_load.
        const int mu0 = mu[2 * bn];
        const int mu1 = mu[2 * bn + 1];
        const float* patch_base = img + (((b * C + c) * H + mu0) * W + mu1);

        // One 4B-aligned 16B load — gfx9+ global HW handles unaligned dwordx4.
        f32x4 v = *reinterpret_cast<const f32x4*>(patch_base + ky * W + kx4 * 4);

        f32x4 o = v * g;

        // Streaming output: nontemporal so the 100.7 MB write doesn't evict
        // the 12.6 MB image from L2.
        f32x4* out4 = reinterpret_cast<f32x4*>(out) + (rem * 256 + local);
        __builtin_nontemporal_store(o, out4);
    }
}

extern "C" void kernel_launch(void* const* d_in, const int* in_sizes, int n_in,
                              void* d_out, int out_size, void* d_ws, size_t ws_size,
                              hipStream_t stream) {
    const float* img   = (const float*)d_in[0];
    const int*   mu    = (const int*)d_in[1];
    const float* gauss = (const float*)d_in[2];
    float*       out   = (float*)d_out;

    rgte_kernel<<<B * N * C / 4, 256, 0, stream>>>(img, mu, gauss, out);
}